// Round 4
// baseline (112.874 us; speedup 1.0000x reference)
//
#include <hip/hip_runtime.h>

typedef short s8v __attribute__((ext_vector_type(8)));    // 8 bf16 (raw bits) = 4 VGPRs
typedef float f4v __attribute__((ext_vector_type(4)));    // MFMA accumulator

#define GAS __attribute__((address_space(1)))
#define LAS __attribute__((address_space(3)))

constexpr int KDIM = 128;
constexpr float INV_COS = 1.0f / 128.0f;   // 1/COS_SCALE
constexpr int NT = 128;                     // 64-row tiles per dimension
constexpr int NTILES = NT * (NT + 1) / 2;   // 8256 upper-tri tiles

// ---- fp32 -> bf16 (RNE) ----
__device__ inline unsigned short f2bf(float f) {
    unsigned u = __float_as_uint(f);
    u += 0x7fffu + ((u >> 16) & 1u);
    return (unsigned short)(u >> 16);
}

__global__ __launch_bounds__(256) void k_convert(const float* __restrict__ X,
                                                 unsigned short* __restrict__ Xb) {
    int idx = (blockIdx.x * 256 + threadIdx.x) * 4;
    float4 v = *(const float4*)(X + idx);
    ushort4 o;
    o.x = f2bf(v.x); o.y = f2bf(v.y); o.z = f2bf(v.z); o.w = f2bf(v.w);
    *(ushort4*)(Xb + idx) = o;
}

// ---- symmetric 64x64-tile gemm + exp + row/col sums ----
// Tile (by,bx), bx>=by. 32 KiB LDS -> 5 blocks/CU (20 waves/CU).
// partial[row][256]: row r (tile-row b=r>>6) gets row-sum slots {2bx+wn: bx>=b}
// = [2b,256) and col-sum slots {2by+wm: by<b} = [0,2b). Exact cover, no atomics.
__global__ __launch_bounds__(256) void k_gemm_rowsum(const unsigned short* __restrict__ Xb,
                                                     float* __restrict__ partial,
                                                     unsigned* __restrict__ counter) {
    __shared__ unsigned short ldsA[64 * 128];   // 16 KiB
    __shared__ unsigned short ldsB[64 * 128];   // 16 KiB

    if (blockIdx.x == 0 && threadIdx.x == 0) *counter = 0;  // for k_finalize

    // closed-form upper-triangular decode: tri(b) = b*(2*NT+1-b)/2
    const int idx = blockIdx.x;
    int by = (int)((2.0f * NT + 1.0f -
                    sqrtf((2.0f * NT + 1.0f) * (2.0f * NT + 1.0f) - 8.0f * (float)idx)) * 0.5f);
    if (by < 0) by = 0;
    if (by > NT - 1) by = NT - 1;
    while (by > 0 && by * (2 * NT + 1 - by) / 2 > idx) --by;
    while ((by + 1) * (2 * NT - by) / 2 <= idx) ++by;
    const int bx = by + (idx - by * (2 * NT + 1 - by) / 2);
    const bool offdiag = (bx != by);

    const int tid  = threadIdx.x;
    const int wave = tid >> 6;
    const int lane = tid & 63;
    const int rA = by * 64;
    const int rB = bx * 64;

    // ---- staging: XOR-swizzled 16B chunks; slot (r,cph) holds chunk cph^(r&15) ----
    {
        const int lr4 = lane >> 4;
        const int cph = lane & 15;
#pragma unroll
        for (int t = 0; t < 4; ++t) {
            int g = wave * 4 + t;           // 16 groups of 4 rows
            int r_loc = g * 4 + lr4;        // 0..63
            int c_log = cph ^ (r_loc & 15);
            const unsigned short* ga = Xb + (size_t)(rA + r_loc) * KDIM + c_log * 8;
            const unsigned short* gb = Xb + (size_t)(rB + r_loc) * KDIM + c_log * 8;
            __builtin_amdgcn_global_load_lds((const GAS void*)ga, (LAS void*)&ldsA[g * 512], 16, 0, 0);
            __builtin_amdgcn_global_load_lds((const GAS void*)gb, (LAS void*)&ldsB[g * 512], 16, 0, 0);
        }
    }
    __syncthreads();

    const int q    = lane >> 4;    // quad 0..3
    const int mrow = lane & 15;
    const int wm   = wave >> 1;    // 2x2 wave grid over 64x64 tile
    const int wn   = wave & 1;

    f4v acc[2][2];
#pragma unroll
    for (int a = 0; a < 2; ++a)
#pragma unroll
        for (int b = 0; b < 2; ++b)
            acc[a][b] = (f4v){0.f, 0.f, 0.f, 0.f};

#pragma unroll
    for (int ks = 0; ks < 4; ++ks) {               // K-steps of 32
        s8v af[2], bfr[2];
        int cp = (ks * 4 + q) ^ mrow;              // row&15 == mrow for all frags
#pragma unroll
        for (int mi = 0; mi < 2; ++mi) {
            int ra = wm * 32 + mi * 16 + mrow;
            int rb = wn * 32 + mi * 16 + mrow;
            af[mi]  = *(const s8v*)&ldsA[(ra * 16 + cp) * 8];
            bfr[mi] = *(const s8v*)&ldsB[(rb * 16 + cp) * 8];
        }
#pragma unroll
        for (int mi = 0; mi < 2; ++mi)
#pragma unroll
            for (int ni = 0; ni < 2; ++ni)
                acc[mi][ni] = __builtin_amdgcn_mfma_f32_16x16x32_bf16(af[mi], bfr[ni], acc[mi][ni], 0, 0, 0);
    }

    // ---- epilogue: e = exp(1+g/128); lane holds
    // G[wm*32+mi*16+q*4+t][wn*32+ni*16+mrow]
    float rsum[2][4];
    float csum[2] = {0.f, 0.f};
#pragma unroll
    for (int mi = 0; mi < 2; ++mi)
#pragma unroll
        for (int t = 0; t < 4; ++t)
            rsum[mi][t] = 0.f;

#pragma unroll
    for (int mi = 0; mi < 2; ++mi)
#pragma unroll
        for (int ni = 0; ni < 2; ++ni)
#pragma unroll
            for (int t = 0; t < 4; ++t) {
                float e = __expf(fmaf(acc[mi][ni][t], INV_COS, 1.0f));
                rsum[mi][t] += e;
                csum[ni]    += e;
            }

    // row-sums: reduce across mrow (16 cols in this wave's half) via xor 1,2,4,8
#pragma unroll
    for (int mi = 0; mi < 2; ++mi)
#pragma unroll
        for (int t = 0; t < 4; ++t) {
            float v = rsum[mi][t];
            v += __shfl_xor(v, 1);
            v += __shfl_xor(v, 2);
            v += __shfl_xor(v, 4);
            v += __shfl_xor(v, 8);
            rsum[mi][t] = v;
        }

    // lane mrow<8 writes row (mi=mrow>>2, t=mrow&3) of its quad
    {
        float outv = 0.f;
#pragma unroll
        for (int mi = 0; mi < 2; ++mi)
#pragma unroll
            for (int t = 0; t < 4; ++t)
                if (mrow == mi * 4 + t) outv = rsum[mi][t];
        if (mrow < 8) {
            int row_loc = wm * 32 + (mrow >> 2) * 16 + q * 4 + (mrow & 3);
            partial[(size_t)(rA + row_loc) * 256 + (bx * 2 + wn)] = outv;
        }
    }

    if (offdiag) {
        // col-sums: reduce across q via xor 16,32 -> sum over this wave's 32 rows
#pragma unroll
        for (int ni = 0; ni < 2; ++ni) {
            float v = csum[ni];
            v += __shfl_xor(v, 16);
            v += __shfl_xor(v, 32);
            csum[ni] = v;
        }
        if (q == 0) {
#pragma unroll
            for (int ni = 0; ni < 2; ++ni) {
                int col_loc = wn * 32 + ni * 16 + mrow;
                partial[(size_t)(rB + col_loc) * 256 + (by * 2 + wm)] = csum[ni];
            }
        }
    }
}

// ---- finalize: one wave per pair; deterministic block sums; last block reduces ----
__global__ __launch_bounds__(256) void k_finalize(const float* __restrict__ X,
                                                  const float* __restrict__ partial,
                                                  float* __restrict__ blocksum,
                                                  unsigned* __restrict__ counter,
                                                  float* __restrict__ out) {
    __shared__ float ls[4];
    __shared__ int lastflag;
    const int tid = threadIdx.x;
    const int wave = tid >> 6, lane = tid & 63;
    const int p = blockIdx.x * 4 + wave;         // 4096 pairs
    const int i = 2 * p, j = i + 1;

    const float* pri = partial + (size_t)i * 256;
    const float* prj = partial + (size_t)j * 256;
    float pi = pri[lane] + pri[lane + 64] + pri[lane + 128] + pri[lane + 192];
    float pj = prj[lane] + prj[lane + 64] + prj[lane + 128] + prj[lane + 192];
    float xi0 = X[(size_t)i * 128 + lane], xi1 = X[(size_t)i * 128 + 64 + lane];
    float xj0 = X[(size_t)j * 128 + lane], xj1 = X[(size_t)j * 128 + 64 + lane];
    float dii = xi0 * xi0 + xi1 * xi1;
    float dij = xi0 * xj0 + xi1 * xj1;
    float djj = xj0 * xj0 + xj1 * xj1;

#pragma unroll
    for (int m = 1; m < 64; m <<= 1) {
        pi  += __shfl_xor(pi, m);
        pj  += __shfl_xor(pj, m);
        dii += __shfl_xor(dii, m);
        dij += __shfl_xor(dij, m);
        djj += __shfl_xor(djj, m);
    }
    if (lane == 0) {
        dii *= INV_COS; dij *= INV_COS; djj *= INV_COS;
        float eii = __expf(1.0f + dii);
        float eij = __expf(1.0f + dij);
        float ejj = __expf(1.0f + djj);
        float dissim = (pi - eii - eij) + (pj - eij - ejj);
        float J = __logf(1e-8f + dissim) - dij;
        ls[wave] = (J > 0.f) ? J * J : 0.f;
    }
    __syncthreads();
    if (tid == 0) {
        blocksum[blockIdx.x] = ls[0] + ls[1] + ls[2] + ls[3];
        __threadfence();                          // release blocksum
        unsigned old = atomicAdd(counter, 1u);
        lastflag = (old == 1023u);
    }
    __syncthreads();
    if (lastflag) {
        __threadfence();                          // acquire all blocksums
        float s = blocksum[tid] + blocksum[tid + 256] + blocksum[tid + 512] + blocksum[tid + 768];
#pragma unroll
        for (int m = 1; m < 64; m <<= 1) s += __shfl_xor(s, m);
        if ((tid & 63) == 0) ls[tid >> 6] = s;
        __syncthreads();
        if (tid == 0) out[0] = (ls[0] + ls[1] + ls[2] + ls[3]) * (1.0f / 16384.0f);
    }
}

extern "C" void kernel_launch(void* const* d_in, const int* in_sizes, int n_in,
                              void* d_out, int out_size, void* d_ws, size_t ws_size,
                              hipStream_t stream) {
    const float* X = (const float*)d_in[0];
    char* ws = (char*)d_ws;
    unsigned short* Xb = (unsigned short*)ws;            // 2 MiB bf16 input
    float* partial   = (float*)(ws + (2u << 20));        // 8 MiB: partial[8192][256]
    float* blocksum  = (float*)(ws + (10u << 20));       // 4 KiB
    unsigned* counter = (unsigned*)(ws + (11u << 20));   // 4 B
    float* out       = (float*)d_out;

    hipLaunchKernelGGL(k_convert,     dim3(1024),   dim3(256), 0, stream, X, Xb);
    hipLaunchKernelGGL(k_gemm_rowsum, dim3(NTILES), dim3(256), 0, stream, Xb, partial, counter);
    hipLaunchKernelGGL(k_finalize,    dim3(1024),   dim3(256), 0, stream, X, partial, blocksum, counter, out);
}

// Round 5
// 86.740 us; speedup vs baseline: 1.3013x; 1.3013x over previous
//
#include <hip/hip_runtime.h>

typedef short s8v __attribute__((ext_vector_type(8)));    // 8 bf16 (raw bits) = 4 VGPRs
typedef float f4v __attribute__((ext_vector_type(4)));    // MFMA accumulator

#define GAS __attribute__((address_space(1)))
#define LAS __attribute__((address_space(3)))

constexpr int KDIM = 128;
constexpr float INV_COS = 1.0f / 128.0f;   // 1/COS_SCALE

// ---- fp32 -> bf16 (RNE) ----
__device__ inline unsigned short f2bf(float f) {
    unsigned u = __float_as_uint(f);
    u += 0x7fffu + ((u >> 16) & 1u);
    return (unsigned short)(u >> 16);
}

__global__ __launch_bounds__(256) void k_convert(const float* __restrict__ X,
                                                 unsigned short* __restrict__ Xb) {
    int idx = (blockIdx.x * 256 + threadIdx.x) * 4;
    float4 v = *(const float4*)(X + idx);
    ushort4 o;
    o.x = f2bf(v.x); o.y = f2bf(v.y); o.z = f2bf(v.z); o.w = f2bf(v.w);
    *(ushort4*)(Xb + idx) = o;
}

// ---- symmetric 128x128-tile gemm + exp + row/col sums (R3-verified) ----
// Tile (by,bx), bx>=by only. Off-diagonal tiles contribute row-sums to A-rows
// and col-sums (= mirror row-sums) to B-rows.
// partial[row][128] slot map for row r in tile-row b: row-sum slots
// {2bx+wn : bx>=b} = [2b,128), col-sum slots {2by+wm : by<b} = [0,2b).
// Exact cover, each slot written once, no atomics, no zero-init needed.
__global__ __launch_bounds__(256) void k_gemm_rowsum(const unsigned short* __restrict__ Xb,
                                                     float* __restrict__ partial) {
    __shared__ unsigned short ldsA[128 * 128];   // 32 KiB
    __shared__ unsigned short ldsB[128 * 128];   // 32 KiB

    // linear block id -> upper-triangular (by, bx), 64x64 tile grid
    int rem = blockIdx.x;
    int by = 0;
    while (rem >= 64 - by) { rem -= 64 - by; ++by; }
    const int bx = by + rem;
    const bool offdiag = (bx != by);

    const int tid  = threadIdx.x;
    const int wave = tid >> 6;
    const int lane = tid & 63;
    const int rA = by * 128;
    const int rB = bx * 128;

    // ---- staging: XOR-swizzled 16B chunks; slot (r, cph) holds chunk cph^(r&15) ----
    {
        const int lr4 = lane >> 4;
        const int cph = lane & 15;
#pragma unroll
        for (int t = 0; t < 8; ++t) {
            int g = wave * 8 + t;
            int r_loc = g * 4 + lr4;
            int c_log = cph ^ (r_loc & 15);
            const unsigned short* ga = Xb + (size_t)(rA + r_loc) * KDIM + c_log * 8;
            const unsigned short* gb = Xb + (size_t)(rB + r_loc) * KDIM + c_log * 8;
            __builtin_amdgcn_global_load_lds((const GAS void*)ga, (LAS void*)&ldsA[g * 512], 16, 0, 0);
            __builtin_amdgcn_global_load_lds((const GAS void*)gb, (LAS void*)&ldsB[g * 512], 16, 0, 0);
        }
    }
    __syncthreads();

    const int q    = lane >> 4;    // quad 0..3
    const int mrow = lane & 15;
    const int wm   = wave >> 1;    // 2x2 wave grid over 128x128 tile
    const int wn   = wave & 1;

    f4v acc[4][4];
#pragma unroll
    for (int a = 0; a < 4; ++a)
#pragma unroll
        for (int b = 0; b < 4; ++b)
            acc[a][b] = (f4v){0.f, 0.f, 0.f, 0.f};

#pragma unroll
    for (int ks = 0; ks < 4; ++ks) {               // K-steps of 32
        s8v af[4], bfr[4];
        int cp = (ks * 4 + q) ^ mrow;
#pragma unroll
        for (int mi = 0; mi < 4; ++mi) {
            int ra = wm * 64 + mi * 16 + mrow;
            int rb = wn * 64 + mi * 16 + mrow;
            af[mi]  = *(const s8v*)&ldsA[(ra * 16 + cp) * 8];
            bfr[mi] = *(const s8v*)&ldsB[(rb * 16 + cp) * 8];
        }
#pragma unroll
        for (int mi = 0; mi < 4; ++mi)
#pragma unroll
            for (int ni = 0; ni < 4; ++ni)
                acc[mi][ni] = __builtin_amdgcn_mfma_f32_16x16x32_bf16(af[mi], bfr[ni], acc[mi][ni], 0, 0, 0);
    }

    // ---- epilogue: e = exp(1+g/128); lane holds
    // G[wm*64+mi*16+q*4+t][wn*64+ni*16+mrow]
    float rsum[4][4];
    float csum[4] = {0.f, 0.f, 0.f, 0.f};
#pragma unroll
    for (int mi = 0; mi < 4; ++mi)
#pragma unroll
        for (int t = 0; t < 4; ++t)
            rsum[mi][t] = 0.f;

#pragma unroll
    for (int mi = 0; mi < 4; ++mi)
#pragma unroll
        for (int ni = 0; ni < 4; ++ni)
#pragma unroll
            for (int t = 0; t < 4; ++t) {
                float e = __expf(fmaf(acc[mi][ni][t], INV_COS, 1.0f));
                rsum[mi][t] += e;
                csum[ni]    += e;
            }

    // row-sums: reduce across mrow (16 cols) via xor 1,2,4,8
#pragma unroll
    for (int mi = 0; mi < 4; ++mi)
#pragma unroll
        for (int t = 0; t < 4; ++t) {
            float v = rsum[mi][t];
            v += __shfl_xor(v, 1);
            v += __shfl_xor(v, 2);
            v += __shfl_xor(v, 4);
            v += __shfl_xor(v, 8);
            rsum[mi][t] = v;
        }

    // lane c (=mrow) writes row (mi=c>>2, t=c&3) of its quad
    {
        const int c = mrow;
        float outv = 0.f;
#pragma unroll
        for (int mi = 0; mi < 4; ++mi)
#pragma unroll
            for (int t = 0; t < 4; ++t)
                if ((mi * 4 + t) == c) outv = rsum[mi][t];
        int row_loc = wm * 64 + (c >> 2) * 16 + q * 4 + (c & 3);
        partial[(size_t)(rA + row_loc) * 128 + (bx * 2 + wn)] = outv;
    }

    if (offdiag) {
        // col-sums: reduce across q (4 row-groups) via xor 16,32
#pragma unroll
        for (int ni = 0; ni < 4; ++ni) {
            float v = csum[ni];
            v += __shfl_xor(v, 16);
            v += __shfl_xor(v, 32);
            csum[ni] = v;
        }
        if (q == 0) {
#pragma unroll
            for (int ni = 0; ni < 4; ++ni) {
                int col_loc = wn * 64 + ni * 16 + mrow;
                partial[(size_t)(rB + col_loc) * 128 + (by * 2 + wm)] = csum[ni];
            }
        }
    }
}

// ---- finalize 1: one wave per pair, deterministic per-block sums ----
__global__ __launch_bounds__(256) void k_finalize1(const float* __restrict__ X,
                                                   const float* __restrict__ partial,
                                                   float* __restrict__ blocksum) {
    __shared__ float ls[4];
    int wave = threadIdx.x >> 6, lane = threadIdx.x & 63;
    int p = blockIdx.x * 4 + wave;
    int i = 2 * p, j = i + 1;

    float pi = partial[(size_t)i * 128 + lane] + partial[(size_t)i * 128 + 64 + lane];
    float pj = partial[(size_t)j * 128 + lane] + partial[(size_t)j * 128 + 64 + lane];
    float xi0 = X[(size_t)i * 128 + lane], xi1 = X[(size_t)i * 128 + 64 + lane];
    float xj0 = X[(size_t)j * 128 + lane], xj1 = X[(size_t)j * 128 + 64 + lane];
    float dii = xi0 * xi0 + xi1 * xi1;
    float dij = xi0 * xj0 + xi1 * xj1;
    float djj = xj0 * xj0 + xj1 * xj1;

#pragma unroll
    for (int m = 1; m < 64; m <<= 1) {
        pi  += __shfl_xor(pi, m);
        pj  += __shfl_xor(pj, m);
        dii += __shfl_xor(dii, m);
        dij += __shfl_xor(dij, m);
        djj += __shfl_xor(djj, m);
    }
    if (lane == 0) {
        dii *= INV_COS; dij *= INV_COS; djj *= INV_COS;
        float eii = __expf(1.0f + dii);
        float eij = __expf(1.0f + dij);
        float ejj = __expf(1.0f + djj);
        float dissim = (pi - eii - eij) + (pj - eij - ejj);
        float J = __logf(1e-8f + dissim) - dij;
        ls[wave] = (J > 0.f) ? J * J : 0.f;
    }
    __syncthreads();
    if (threadIdx.x == 0)
        blocksum[blockIdx.x] = ls[0] + ls[1] + ls[2] + ls[3];
}

// ---- finalize 2: single block reduces 1024 block sums ----
__global__ __launch_bounds__(256) void k_finalize2(const float* __restrict__ blocksum,
                                                   float* __restrict__ out) {
    __shared__ float ls[4];
    int t = threadIdx.x;
    float s = blocksum[t] + blocksum[t + 256] + blocksum[t + 512] + blocksum[t + 768];
#pragma unroll
    for (int m = 1; m < 64; m <<= 1) s += __shfl_xor(s, m);
    if ((t & 63) == 0) ls[t >> 6] = s;
    __syncthreads();
    if (t == 0) out[0] = (ls[0] + ls[1] + ls[2] + ls[3]) * (1.0f / 16384.0f);
}

extern "C" void kernel_launch(void* const* d_in, const int* in_sizes, int n_in,
                              void* d_out, int out_size, void* d_ws, size_t ws_size,
                              hipStream_t stream) {
    const float* X = (const float*)d_in[0];
    char* ws = (char*)d_ws;
    unsigned short* Xb = (unsigned short*)ws;            // 2 MiB bf16 input
    float* partial  = (float*)(ws + (2u << 20));         // 4 MiB: partial[8192][128]
    float* blocksum = (float*)(ws + (6u << 20));         // 4 KiB
    float* out      = (float*)d_out;

    hipLaunchKernelGGL(k_convert,     dim3(1024), dim3(256), 0, stream, X, Xb);
    hipLaunchKernelGGL(k_gemm_rowsum, dim3(2080), dim3(256), 0, stream, Xb, partial);
    hipLaunchKernelGGL(k_finalize1,   dim3(1024), dim3(256), 0, stream, X, partial, blocksum);
    hipLaunchKernelGGL(k_finalize2,   dim3(1),    dim3(256), 0, stream, blocksum, out);
}